// Round 7
// baseline (1093.934 us; speedup 1.0000x reference)
//
#include <hip/hip_runtime.h>
#include <hip/hip_bf16.h>
#include <math.h>

#define NN 8192
#define FF 256
#define ALPHA 0.2f
#define CAP 512

// MEASUREMENT ROUND: in-kernel idempotent repetition to lift each dispatch
// above the harness's ~157us poison-fills so rocprof top-5 shows per-kernel
// dur/FETCH/VALUBusy. Divide dur_us by REP_* to get per-iteration cost.
#define REP_GEMM 16
#define REP_STREAM 4
#define REP_ATTN 16

typedef float f32x4 __attribute__((ext_vector_type(4)));

// ---------------------------------------------------------------------------
__global__ __launch_bounds__(256) void transpose_w_kernel(
    const float* __restrict__ W, float4* __restrict__ Wtv) {
  const int k4 = blockIdx.x;
  const int c  = threadIdx.x;
  const float4* W4 = reinterpret_cast<const float4*>(W);
  Wtv[k4 * 256 + c] = W4[c * 64 + k4];
}

// ---------------------------------------------------------------------------
__global__ __launch_bounds__(256) void gemm_h_kernel(
    const float* __restrict__ x, const float4* __restrict__ Wtv,
    const float* __restrict__ asrc, const float* __restrict__ adst,
    float* __restrict__ a_src, float* __restrict__ a_dst,
    __hip_bfloat16* __restrict__ h_bf) {
  __shared__ float4 xt4[16 * 64];
  __shared__ float pr[2][16][4];
  const int t = threadIdx.x;
  const int lane = t & 63, wid = t >> 6;
  const int i0 = blockIdx.x * 16;
  const int c = t;

  for (int rep = 0; rep < REP_GEMM; ++rep) {
    asm volatile("" ::: "memory");   // defeat cross-rep load CSE/hoisting

    const float4* x4 = reinterpret_cast<const float4*>(x);
#pragma unroll
    for (int q = 0; q < 4; ++q) {
      int idx = q * 256 + t;
      xt4[idx] = x4[(size_t)i0 * 64 + idx];
    }
    __syncthreads();

    const float asv = asrc[c];
    const float adv = adst[c];
    float acc[16];
#pragma unroll
    for (int r = 0; r < 16; ++r) acc[r] = 0.f;
    for (int k4 = 0; k4 < 64; ++k4) {
      float4 w4 = Wtv[k4 * 256 + c];
#pragma unroll
      for (int r = 0; r < 16; ++r) {
        float4 xv = xt4[r * 64 + k4];
        acc[r] = fmaf(w4.x, xv.x, acc[r]);
        acc[r] = fmaf(w4.y, xv.y, acc[r]);
        acc[r] = fmaf(w4.z, xv.z, acc[r]);
        acc[r] = fmaf(w4.w, xv.w, acc[r]);
      }
    }

#pragma unroll
    for (int r = 0; r < 16; ++r)
      h_bf[(size_t)(i0 + r) * FF + c] = __float2bfloat16(acc[r]);

#pragma unroll
    for (int r = 0; r < 16; ++r) {
      float ps = acc[r] * asv;
      float pd = acc[r] * adv;
#pragma unroll
      for (int o = 32; o; o >>= 1) {
        ps += __shfl_down(ps, o, 64);
        pd += __shfl_down(pd, o, 64);
      }
      if (lane == 0) { pr[0][r][wid] = ps; pr[1][r][wid] = pd; }
    }
    __syncthreads();
    if (t < 32) {
      int r = t & 15, which = t >> 4;
      float s4 = pr[which][r][0] + pr[which][r][1] + pr[which][r][2] + pr[which][r][3];
      if (which == 0) a_src[i0 + r] = s4;
      else            a_dst[i0 + r] = s4;
    }
  }
}

// ---------------------------------------------------------------------------
__global__ __launch_bounds__(256) void stream_kernel(
    const float* __restrict__ adj, int* __restrict__ cnt_g,
    unsigned* __restrict__ idx_g) {
  const int t = threadIdx.x;
  const int lane = t & 63, w = t >> 6;
  const int i = blockIdx.x * 4 + w;
  const f32x4* adj4 = reinterpret_cast<const f32x4*>(adj + (size_t)i * NN);
  unsigned* rowidx = idx_g + (size_t)i * CAP;

  for (int rep = 0; rep < REP_STREAM; ++rep) {
    asm volatile("" ::: "memory");

    int cnt = 0;
#pragma unroll
    for (int half = 0; half < 2; ++half) {
      f32x4 v[16];
#pragma unroll
      for (int q = 0; q < 16; ++q)
        v[q] = adj4[half * 1024 + q * 64 + lane];
      unsigned long long m = 0ull;
#pragma unroll
      for (int q = 0; q < 16; ++q) {
#pragma unroll
        for (int u = 0; u < 4; ++u)
          m |= (v[q][u] > 0.f ? 1ull : 0ull) << (q * 4 + u);
      }
      int c_t = __popcll(m);
      int scan = c_t;
#pragma unroll
      for (int d = 1; d < 64; d <<= 1) {
        int nv = __shfl_up(scan, d, 64);
        if (lane >= d) scan += nv;
      }
      int tot = __shfl(scan, 63, 64);
      int off = cnt + scan - c_t;
      while (m) {
        int b = __builtin_ctzll(m);
        m &= m - 1ull;
        if (off < CAP)
          rowidx[off] = (unsigned)(half * 4096 + ((b >> 2) << 8) + (lane << 2) + (b & 3));
        ++off;
      }
      cnt += tot;
    }
    if (lane == 0) cnt_g[i] = cnt > CAP ? CAP : cnt;
  }
}

// ---------------------------------------------------------------------------
__global__ __launch_bounds__(256) void attn_kernel(
    const int* __restrict__ cnt_g, const unsigned* __restrict__ idx_g,
    const float* __restrict__ a_src, const float* __restrict__ a_dst,
    const __hip_bfloat16* __restrict__ h_bf, float* __restrict__ out) {
  __shared__ uint2 s_edge[4][CAP];   // 16 KB; per-wave private slice
  const int t = threadIdx.x;
  const int lane = t & 63, w = t >> 6;
  const int i = blockIdx.x * 4 + w;
  uint2* edge = s_edge[w];

  for (int rep = 0; rep < REP_ATTN; ++rep) {
    asm volatile("" ::: "memory");

    const float a_d = a_dst[i];
    const int cnt = cnt_g[i];
    const unsigned* rowidx = idx_g + (size_t)i * CAP;

    float lmax = 0.f;
    for (int p = lane; p < cnt; p += 64) {
      int j = (int)rowidx[p];
      float s = a_src[j] + a_d;
      float lk = s > 0.f ? s : ALPHA * s;
      edge[p].x = (unsigned)j;
      edge[p].y = __float_as_uint(lk);
      lmax = fmaxf(lmax, lk);
    }
#pragma unroll
    for (int d = 32; d; d >>= 1) lmax = fmaxf(lmax, __shfl_xor(lmax, d, 64));

    float lsum = 0.f;
    for (int p = lane; p < cnt; p += 64) {
      float e = __expf(__uint_as_float(edge[p].y) - lmax);
      edge[p].y = __float_as_uint(e);
      lsum += e;
    }
#pragma unroll
    for (int d = 32; d; d >>= 1) lsum += __shfl_xor(lsum, d, 64);
    const float inv = 1.f / (lsum + 1e-8f);

    float a0 = 0.f, a1 = 0.f, a2 = 0.f, a3 = 0.f;
    int p = 0;
    for (; p + 4 <= cnt; p += 4) {
      uint2 e0 = edge[p], e1 = edge[p + 1], e2 = edge[p + 2], e3 = edge[p + 3];
      uint2 h0 = *((const uint2*)(h_bf + (size_t)e0.x * FF) + lane);
      uint2 h1 = *((const uint2*)(h_bf + (size_t)e1.x * FF) + lane);
      uint2 h2 = *((const uint2*)(h_bf + (size_t)e2.x * FF) + lane);
      uint2 h3 = *((const uint2*)(h_bf + (size_t)e3.x * FF) + lane);
      float w0 = __uint_as_float(e0.y), w1 = __uint_as_float(e1.y);
      float w2 = __uint_as_float(e2.y), w3 = __uint_as_float(e3.y);
      a0 = fmaf(w0, __uint_as_float(h0.x << 16), a0);
      a1 = fmaf(w0, __uint_as_float(h0.x & 0xffff0000u), a1);
      a2 = fmaf(w0, __uint_as_float(h0.y << 16), a2);
      a3 = fmaf(w0, __uint_as_float(h0.y & 0xffff0000u), a3);
      a0 = fmaf(w1, __uint_as_float(h1.x << 16), a0);
      a1 = fmaf(w1, __uint_as_float(h1.x & 0xffff0000u), a1);
      a2 = fmaf(w1, __uint_as_float(h1.y << 16), a2);
      a3 = fmaf(w1, __uint_as_float(h1.y & 0xffff0000u), a3);
      a0 = fmaf(w2, __uint_as_float(h2.x << 16), a0);
      a1 = fmaf(w2, __uint_as_float(h2.x & 0xffff0000u), a1);
      a2 = fmaf(w2, __uint_as_float(h2.y << 16), a2);
      a3 = fmaf(w2, __uint_as_float(h2.y & 0xffff0000u), a3);
      a0 = fmaf(w3, __uint_as_float(h3.x << 16), a0);
      a1 = fmaf(w3, __uint_as_float(h3.x & 0xffff0000u), a1);
      a2 = fmaf(w3, __uint_as_float(h3.y << 16), a2);
      a3 = fmaf(w3, __uint_as_float(h3.y & 0xffff0000u), a3);
    }
    for (; p < cnt; ++p) {
      uint2 e0 = edge[p];
      float w0 = __uint_as_float(e0.y);
      uint2 h0 = *((const uint2*)(h_bf + (size_t)e0.x * FF) + lane);
      a0 = fmaf(w0, __uint_as_float(h0.x << 16), a0);
      a1 = fmaf(w0, __uint_as_float(h0.x & 0xffff0000u), a1);
      a2 = fmaf(w0, __uint_as_float(h0.y << 16), a2);
      a3 = fmaf(w0, __uint_as_float(h0.y & 0xffff0000u), a3);
    }

    float4 o4;
    o4.x = a0 * inv; o4.y = a1 * inv; o4.z = a2 * inv; o4.w = a3 * inv;
    o4.x = o4.x > 0.f ? o4.x : (__expf(o4.x) - 1.f);
    o4.y = o4.y > 0.f ? o4.y : (__expf(o4.y) - 1.f);
    o4.z = o4.z > 0.f ? o4.z : (__expf(o4.z) - 1.f);
    o4.w = o4.w > 0.f ? o4.w : (__expf(o4.w) - 1.f);
    reinterpret_cast<float4*>(out)[(size_t)i * 64 + lane] = o4;
  }
}

// ---------------------------------------------------------------------------
extern "C" void kernel_launch(void* const* d_in, const int* in_sizes, int n_in,
                              void* d_out, int out_size, void* d_ws, size_t ws_size,
                              hipStream_t stream) {
  const float* x        = (const float*)d_in[0];   // (8192,256)
  const float* adj      = (const float*)d_in[1];   // (8192,8192)
  const float* W        = (const float*)d_in[2];   // (256,256)
  const float* attn_src = (const float*)d_in[3];   // (1,256)
  const float* attn_dst = (const float*)d_in[4];   // (1,256)
  float* out = (float*)d_out;                      // (8192,256) fp32

  // ws: a_src 32K | a_dst 32K | h_bf 4M | Wtv 256K | cnt 32K | idx 16M
  char* ws = (char*)d_ws;
  float* a_src = (float*)ws;
  float* a_dst = (float*)(ws + 32768);
  __hip_bfloat16* h_bf = (__hip_bfloat16*)(ws + 65536);
  float4* Wtv = (float4*)(ws + 65536 + (size_t)NN * FF * 2);
  int* cnt_g = (int*)(ws + 65536 + (size_t)NN * FF * 2 + 262144);
  unsigned* idx_g = (unsigned*)(ws + 65536 + (size_t)NN * FF * 2 + 262144 + 32768);

  hipLaunchKernelGGL(transpose_w_kernel, dim3(64), dim3(256), 0, stream, W, Wtv);
  hipLaunchKernelGGL(gemm_h_kernel, dim3(NN / 16), dim3(256), 0, stream,
                     x, Wtv, attn_src, attn_dst, a_src, a_dst, h_bf);
  hipLaunchKernelGGL(stream_kernel, dim3(NN / 4), dim3(256), 0, stream,
                     adj, cnt_g, idx_g);
  hipLaunchKernelGGL(attn_kernel, dim3(NN / 4), dim3(256), 0, stream,
                     cnt_g, idx_g, a_src, a_dst, h_bf, out);
}

// Round 8
// 88.681 us; speedup vs baseline: 12.3356x; 12.3356x over previous
//
#include <hip/hip_runtime.h>
#include <hip/hip_bf16.h>
#include <math.h>

#define NN 8192
#define FF 256
#define ALPHA 0.2f
#define CAP 512   // per-row edge cap; nnz ~ Binomial(8192,0.01): mean 82, sd 9 -> 48 sigma

typedef float f32x4 __attribute__((ext_vector_type(4)));
typedef short bf16x8 __attribute__((ext_vector_type(8)));

static __device__ __forceinline__ unsigned short f2bf(float f) {
  __hip_bfloat16 h = __float2bfloat16(f);
  return *reinterpret_cast<unsigned short*>(&h);
}

// ---------------------------------------------------------------------------
// Kernel 0: convert x (8192x256) and W (256x256) fp32 -> bf16.
// 512 blocks x 256 threads; float4 in, ushort4 out, fully coalesced.
// ---------------------------------------------------------------------------
__global__ __launch_bounds__(256) void convert_kernel(
    const float* __restrict__ x, const float* __restrict__ W,
    unsigned short* __restrict__ x_bf, unsigned short* __restrict__ W_bf) {
  const int idx = blockIdx.x * 256 + threadIdx.x;   // 0..131071
  const float4* x4 = reinterpret_cast<const float4*>(x);
  ushort4* xb4 = reinterpret_cast<ushort4*>(x_bf);
#pragma unroll
  for (int q = 0; q < 4; ++q) {
    float4 v = x4[idx + q * 131072];
    ushort4 u;
    u.x = f2bf(v.x); u.y = f2bf(v.y); u.z = f2bf(v.z); u.w = f2bf(v.w);
    xb4[idx + q * 131072] = u;
  }
  if (idx < 16384) {
    float4 v = reinterpret_cast<const float4*>(W)[idx];
    ushort4 u;
    u.x = f2bf(v.x); u.y = f2bf(v.y); u.z = f2bf(v.z); u.w = f2bf(v.w);
    reinterpret_cast<ushort4*>(W_bf)[idx] = u;
  }
}

// ---------------------------------------------------------------------------
// Kernel 1: h = x @ W^T via MFMA bf16 (fp32 accum). Also a_src/a_dst reduced
// from the fp32 accumulators (pre-bf16-rounding, like the reference).
// Block = 32 rows x 256 cols: 4 waves = 2 row-groups x 2 n-halves.
// Wave tile: 16 rows x 128 cols = 8 MFMA n-tiles, K-loop 8 x 32.
// ---------------------------------------------------------------------------
__global__ __launch_bounds__(256) void gemm_mfma_kernel(
    const unsigned short* __restrict__ x_bf, const unsigned short* __restrict__ W_bf,
    const float* __restrict__ asrc, const float* __restrict__ adst,
    float* __restrict__ a_src, float* __restrict__ a_dst,
    unsigned short* __restrict__ h_bf) {
  __shared__ float s_red[2][2][2][16];  // [src/dst][rowgroup][nhalf][row16]
  const int t = threadIdx.x;
  const int lane = t & 63, w = t >> 6;
  const int rg = w >> 1;                // row-group 0/1
  const int nh = w & 1;                 // n-half 0/1
  const int i0 = blockIdx.x * 32;
  const int l16 = lane & 15;            // M-row (A) / N-col (B) within tile
  const int kq  = lane >> 4;            // k-octet selector; also C/D row-group

  // A frag: x_bf[i0+rg*16+l16][kq*8 + k8*32 .. +7]  (16B contiguous)
  const unsigned short* xrow = x_bf + (size_t)(i0 + rg * 16 + l16) * FF + kq * 8;
  // B frag: W_bf[nh*128 + n*16 + l16][kq*8 + k8*32 .. +7]
  const unsigned short* wrow = W_bf + (size_t)(nh * 128 + l16) * FF + kq * 8;

  f32x4 acc[8];
#pragma unroll
  for (int n = 0; n < 8; ++n) acc[n] = (f32x4){0.f, 0.f, 0.f, 0.f};

#pragma unroll
  for (int k8 = 0; k8 < 8; ++k8) {
    bf16x8 a = *reinterpret_cast<const bf16x8*>(xrow + k8 * 32);
#pragma unroll
    for (int n = 0; n < 8; ++n) {
      bf16x8 b = *reinterpret_cast<const bf16x8*>(wrow + (size_t)n * 16 * FF + k8 * 32);
      acc[n] = __builtin_amdgcn_mfma_f32_16x16x32_bf16(a, b, acc[n], 0, 0, 0);
    }
  }

  // Epilogue: h write (C/D: col=lane&15, row=kq*4+r  [m89-verified]) + a reduce
  float ps[4] = {0.f, 0.f, 0.f, 0.f};
  float pd[4] = {0.f, 0.f, 0.f, 0.f};
#pragma unroll
  for (int n = 0; n < 8; ++n) {
    const int c = nh * 128 + n * 16 + l16;
    const float as_c = asrc[c];
    const float ad_c = adst[c];
#pragma unroll
    for (int r = 0; r < 4; ++r) {
      float v = acc[n][r];
      int row = i0 + rg * 16 + kq * 4 + r;
      h_bf[(size_t)row * FF + c] = f2bf(v);
      ps[r] = fmaf(v, as_c, ps[r]);
      pd[r] = fmaf(v, ad_c, pd[r]);
    }
  }
#pragma unroll
  for (int r = 0; r < 4; ++r) {
#pragma unroll
    for (int d = 1; d < 16; d <<= 1) {
      ps[r] += __shfl_xor(ps[r], d, 64);
      pd[r] += __shfl_xor(pd[r], d, 64);
    }
  }
  if (l16 == 0) {
#pragma unroll
    for (int r = 0; r < 4; ++r) {
      s_red[0][rg][nh][kq * 4 + r] = ps[r];
      s_red[1][rg][nh][kq * 4 + r] = pd[r];
    }
  }
  __syncthreads();
  if (t < 32) {
    int rr = t & 15, g = t >> 4;
    a_src[i0 + g * 16 + rr] = s_red[0][g][0][rr] + s_red[0][g][1][rr];
    a_dst[i0 + g * 16 + rr] = s_red[1][g][0][rr] + s_red[1][g][1][rr];
  }
}

// ---------------------------------------------------------------------------
// Kernel 2 (PASS 1): pure adj stream -> compacted edge lists (at BW roofline).
// ---------------------------------------------------------------------------
__global__ __launch_bounds__(256) void stream_kernel(
    const float* __restrict__ adj, int* __restrict__ cnt_g,
    unsigned* __restrict__ idx_g) {
  const int t = threadIdx.x;
  const int lane = t & 63, w = t >> 6;
  const int i = blockIdx.x * 4 + w;
  const f32x4* adj4 = reinterpret_cast<const f32x4*>(adj + (size_t)i * NN);
  unsigned* rowidx = idx_g + (size_t)i * CAP;

  int cnt = 0;
#pragma unroll
  for (int half = 0; half < 2; ++half) {
    f32x4 v[16];
#pragma unroll
    for (int q = 0; q < 16; ++q)
      v[q] = adj4[half * 1024 + q * 64 + lane];
    unsigned long long m = 0ull;
#pragma unroll
    for (int q = 0; q < 16; ++q) {
#pragma unroll
      for (int u = 0; u < 4; ++u)
        m |= (v[q][u] > 0.f ? 1ull : 0ull) << (q * 4 + u);
    }
    int c_t = __popcll(m);
    int scan = c_t;
#pragma unroll
    for (int d = 1; d < 64; d <<= 1) {
      int nv = __shfl_up(scan, d, 64);
      if (lane >= d) scan += nv;
    }
    int tot = __shfl(scan, 63, 64);
    int off = cnt + scan - c_t;
    while (m) {
      int b = __builtin_ctzll(m);
      m &= m - 1ull;
      if (off < CAP)
        rowidx[off] = (unsigned)(half * 4096 + ((b >> 2) << 8) + (lane << 2) + (b & 3));
      ++off;
    }
    cnt += tot;
  }
  if (lane == 0) cnt_g[i] = cnt > CAP ? CAP : cnt;
}

// ---------------------------------------------------------------------------
// Kernel 3 (PASS 2): softmax + aggregation from edge lists (h_bf L2-resident).
// ---------------------------------------------------------------------------
__global__ __launch_bounds__(256) void attn_kernel(
    const int* __restrict__ cnt_g, const unsigned* __restrict__ idx_g,
    const float* __restrict__ a_src, const float* __restrict__ a_dst,
    const unsigned short* __restrict__ h_bf, float* __restrict__ out) {
  __shared__ uint2 s_edge[4][CAP];   // 16 KB; per-wave private slice
  const int t = threadIdx.x;
  const int lane = t & 63, w = t >> 6;
  const int i = blockIdx.x * 4 + w;
  uint2* edge = s_edge[w];

  const float a_d = a_dst[i];
  const int cnt = cnt_g[i];
  const unsigned* rowidx = idx_g + (size_t)i * CAP;

  float lmax = 0.f;   // masked-out entries contribute exact 0.0 in ref max
  for (int p = lane; p < cnt; p += 64) {
    int j = (int)rowidx[p];
    float s = a_src[j] + a_d;
    float lk = s > 0.f ? s : ALPHA * s;
    edge[p].x = (unsigned)j;
    edge[p].y = __float_as_uint(lk);
    lmax = fmaxf(lmax, lk);
  }
#pragma unroll
  for (int d = 32; d; d >>= 1) lmax = fmaxf(lmax, __shfl_xor(lmax, d, 64));

  float lsum = 0.f;
  for (int p = lane; p < cnt; p += 64) {
    float e = __expf(__uint_as_float(edge[p].y) - lmax);
    edge[p].y = __float_as_uint(e);
    lsum += e;
  }
#pragma unroll
  for (int d = 32; d; d >>= 1) lsum += __shfl_xor(lsum, d, 64);
  const float inv = 1.f / (lsum + 1e-8f);

  float a0 = 0.f, a1 = 0.f, a2 = 0.f, a3 = 0.f;
  int p = 0;
  for (; p + 4 <= cnt; p += 4) {
    uint2 e0 = edge[p], e1 = edge[p + 1], e2 = edge[p + 2], e3 = edge[p + 3];
    uint2 h0 = *((const uint2*)(h_bf + (size_t)e0.x * FF) + lane);
    uint2 h1 = *((const uint2*)(h_bf + (size_t)e1.x * FF) + lane);
    uint2 h2 = *((const uint2*)(h_bf + (size_t)e2.x * FF) + lane);
    uint2 h3 = *((const uint2*)(h_bf + (size_t)e3.x * FF) + lane);
    float w0 = __uint_as_float(e0.y), w1 = __uint_as_float(e1.y);
    float w2 = __uint_as_float(e2.y), w3 = __uint_as_float(e3.y);
    a0 = fmaf(w0, __uint_as_float(h0.x << 16), a0);
    a1 = fmaf(w0, __uint_as_float(h0.x & 0xffff0000u), a1);
    a2 = fmaf(w0, __uint_as_float(h0.y << 16), a2);
    a3 = fmaf(w0, __uint_as_float(h0.y & 0xffff0000u), a3);
    a0 = fmaf(w1, __uint_as_float(h1.x << 16), a0);
    a1 = fmaf(w1, __uint_as_float(h1.x & 0xffff0000u), a1);
    a2 = fmaf(w1, __uint_as_float(h1.y << 16), a2);
    a3 = fmaf(w1, __uint_as_float(h1.y & 0xffff0000u), a3);
    a0 = fmaf(w2, __uint_as_float(h2.x << 16), a0);
    a1 = fmaf(w2, __uint_as_float(h2.x & 0xffff0000u), a1);
    a2 = fmaf(w2, __uint_as_float(h2.y << 16), a2);
    a3 = fmaf(w2, __uint_as_float(h2.y & 0xffff0000u), a3);
    a0 = fmaf(w3, __uint_as_float(h3.x << 16), a0);
    a1 = fmaf(w3, __uint_as_float(h3.x & 0xffff0000u), a1);
    a2 = fmaf(w3, __uint_as_float(h3.y << 16), a2);
    a3 = fmaf(w3, __uint_as_float(h3.y & 0xffff0000u), a3);
  }
  for (; p < cnt; ++p) {
    uint2 e0 = edge[p];
    float w0 = __uint_as_float(e0.y);
    uint2 h0 = *((const uint2*)(h_bf + (size_t)e0.x * FF) + lane);
    a0 = fmaf(w0, __uint_as_float(h0.x << 16), a0);
    a1 = fmaf(w0, __uint_as_float(h0.x & 0xffff0000u), a1);
    a2 = fmaf(w0, __uint_as_float(h0.y << 16), a2);
    a3 = fmaf(w0, __uint_as_float(h0.y & 0xffff0000u), a3);
  }

  float4 o4;
  o4.x = a0 * inv; o4.y = a1 * inv; o4.z = a2 * inv; o4.w = a3 * inv;
  o4.x = o4.x > 0.f ? o4.x : (__expf(o4.x) - 1.f);
  o4.y = o4.y > 0.f ? o4.y : (__expf(o4.y) - 1.f);
  o4.z = o4.z > 0.f ? o4.z : (__expf(o4.z) - 1.f);
  o4.w = o4.w > 0.f ? o4.w : (__expf(o4.w) - 1.f);
  reinterpret_cast<float4*>(out)[(size_t)i * 64 + lane] = o4;
}

// ---------------------------------------------------------------------------
extern "C" void kernel_launch(void* const* d_in, const int* in_sizes, int n_in,
                              void* d_out, int out_size, void* d_ws, size_t ws_size,
                              hipStream_t stream) {
  const float* x        = (const float*)d_in[0];   // (8192,256)
  const float* adj      = (const float*)d_in[1];   // (8192,8192)
  const float* W        = (const float*)d_in[2];   // (256,256)
  const float* attn_src = (const float*)d_in[3];   // (1,256)
  const float* attn_dst = (const float*)d_in[4];   // (1,256)
  float* out = (float*)d_out;                      // (8192,256) fp32

  // ws: a_src 32K | a_dst 32K | h_bf 4M | x_bf 4M | W_bf 128K | cnt 32K | idx 16M
  char* ws = (char*)d_ws;
  float* a_src = (float*)ws;
  float* a_dst = (float*)(ws + 32768);
  unsigned short* h_bf = (unsigned short*)(ws + 65536);
  unsigned short* x_bf = (unsigned short*)(ws + 65536 + 4194304);
  unsigned short* W_bf = (unsigned short*)(ws + 65536 + 2 * 4194304);
  int* cnt_g = (int*)(ws + 65536 + 2 * 4194304 + 131072);
  unsigned* idx_g = (unsigned*)(ws + 65536 + 2 * 4194304 + 131072 + 32768);

  hipLaunchKernelGGL(convert_kernel, dim3(512), dim3(256), 0, stream,
                     x, W, x_bf, W_bf);
  hipLaunchKernelGGL(gemm_mfma_kernel, dim3(NN / 32), dim3(256), 0, stream,
                     x_bf, W_bf, attn_src, attn_dst, a_src, a_dst, h_bf);
  hipLaunchKernelGGL(stream_kernel, dim3(NN / 4), dim3(256), 0, stream,
                     adj, cnt_g, idx_g);
  hipLaunchKernelGGL(attn_kernel, dim3(NN / 4), dim3(256), 0, stream,
                     cnt_g, idx_g, a_src, a_dst, h_bf, out);
}